// Round 1
// baseline (1260.583 us; speedup 1.0000x reference)
//
#include <hip/hip_runtime.h>
#include <math.h>

#define TPTS 32            // points per block tile
#define H1   100           // taskmap / vs hidden
#define H3   300           // vv hidden
#define DH0  (TPTS*H1)     // offset of tangent (dh) region inside buf (3200 floats)

__device__ __forceinline__ float eluf(float v)      { return v > 0.f ? v : expm1f(v); }
__device__ __forceinline__ float softplusf(float v) { return v > 20.f ? v : log1pf(expf(v)); }
__device__ __forceinline__ float leakyf(float v)    { return v >= 0.f ? v : 0.01f * v; }
__device__ __forceinline__ float preluf(float v, float a) { return v >= 0.f ? v : a * v; }

// ---------------------------------------------------------------------------
// origin_y = taskmap(zeros(1,2)) — depends only on weights. One small block.
// ---------------------------------------------------------------------------
__global__ void ngdv_origin(
    const float* __restrict__ tm1_w1, const float* __restrict__ tm1_b1,
    const float* __restrict__ tm1_w2, const float* __restrict__ tm1_b2,
    const float* __restrict__ tm1_w3, const float* __restrict__ tm1_b3,
    const float* __restrict__ tm2_w1, const float* __restrict__ tm2_b1,
    const float* __restrict__ tm2_w2, const float* __restrict__ tm2_b2,
    const float* __restrict__ tm2_w3, const float* __restrict__ tm2_b3,
    float* __restrict__ origin_out)
{
    __shared__ float h1[H1], h2[H1], y1o[2], g1[H1], g2[H1];
    const int tid = threadIdx.x;   // 128 threads

    if (tid < H1) h1[tid] = tanhf(tm1_b1[tid]);          // x = 0
    __syncthreads();
    if (tid < H1) {
        float acc = tm1_b2[tid];
        for (int k = 0; k < H1; ++k) acc += h1[k] * tm1_w2[k*H1 + tid];
        h2[tid] = tanhf(acc);
    }
    __syncthreads();
    if (tid < 2) {
        float acc = tm1_b3[tid];
        for (int k = 0; k < H1; ++k) acc += h2[k] * tm1_w3[k*2 + tid];
        y1o[tid] = acc;                                   // + z (=0)
    }
    __syncthreads();
    if (tid < H1) {
        float pre = tm2_b1[tid] + y1o[0]*tm2_w1[tid] + y1o[1]*tm2_w1[H1 + tid];
        g1[tid] = eluf(pre);
    }
    __syncthreads();
    if (tid < H1) {
        float acc = tm2_b2[tid];
        for (int k = 0; k < H1; ++k) acc += g1[k] * tm2_w2[k*H1 + tid];
        g2[tid] = eluf(acc);
    }
    __syncthreads();
    if (tid < 2) {
        float acc = tm2_b3[tid];
        for (int k = 0; k < H1; ++k) acc += g2[k] * tm2_w3[k*2 + tid];
        float s = softplusf(acc);
        origin_out[tid] = (1.f + s) * y1o[tid];
    }
}

// ---------------------------------------------------------------------------
// Main fused kernel: tile of 32 points/block; activations LDS-resident.
// Forward-mode Jacobian (2 tangent columns) interleaved with the primal pass.
// ---------------------------------------------------------------------------
__global__ __launch_bounds__(256, 2) void ngdv_main(
    const float* __restrict__ x,
    const float* __restrict__ tm1_w1, const float* __restrict__ tm1_b1,
    const float* __restrict__ tm1_w2, const float* __restrict__ tm1_b2,
    const float* __restrict__ tm1_w3, const float* __restrict__ tm1_b3,
    const float* __restrict__ tm2_w1, const float* __restrict__ tm2_b1,
    const float* __restrict__ tm2_w2, const float* __restrict__ tm2_b2,
    const float* __restrict__ tm2_w3, const float* __restrict__ tm2_b3,
    const float* __restrict__ vv_w1, const float* __restrict__ vv_b1, const float* __restrict__ vv_a1,
    const float* __restrict__ vv_w2, const float* __restrict__ vv_b2, const float* __restrict__ vv_a2,
    const float* __restrict__ vv_w3, const float* __restrict__ vv_b3,
    const float* __restrict__ vs_w1, const float* __restrict__ vs_b1,
    const float* __restrict__ vs_w2, const float* __restrict__ vs_b2,
    const float* __restrict__ vs_w3, const float* __restrict__ vs_b3,
    const float* __restrict__ origin,
    float* __restrict__ out, int npts)
{
    // big ping-pong buffers: phase A uses [h:100/pt | dh:2x100/pt]; vv phase uses full 300/pt
    __shared__ __align__(16) float bufA[TPTS * H3];
    __shared__ __align__(16) float bufB[TPTS * H3];
    __shared__ float xs[TPTS*2], y1s[TPTS*2], dy1s[TPTS*4], dss[TPTS*4];
    __shared__ float ss[TPTS*2], sigs[TPTS*2], ys[TPTS*2], Js[TPTS*4], lvs[TPTS], dotys[TPTS*2];

    const int tid = threadIdx.x;
    const int p0  = blockIdx.x * TPTS;
    const int j   = tid & 127;     // output-column lane
    const int th  = tid >> 7;      // 0..1 : half-tile selector (16 pts each)
    const int dT  = tid >> 7;      // 0..1 : tangent direction for full-tile maps
    const float a1v = vv_a1[0], a2v = vv_a2[0];

    // ---- load x tile
    if (tid < TPTS*2) {
        int g = p0*2 + tid;
        xs[tid] = (g < npts*2) ? x[g] : 0.f;
    }
    __syncthreads();

    // ---- tm1 L1 (2->100): h1 = tanh(x@W1+b1); tangent seed dh1_d = W1[d]*(1-h1^2)
    if (j < H1) {
        float w0 = tm1_w1[j], w1 = tm1_w1[H1 + j], b = tm1_b1[j];
        #pragma unroll
        for (int tt = 0; tt < 16; ++tt) {
            int t = th*16 + tt;
            float pre = fmaf(xs[t*2+1], w1, fmaf(xs[t*2], w0, b));
            float h = tanhf(pre);
            bufA[t*H1 + j] = h;
            float dd = 1.f - h*h;
            bufA[DH0 + (t*2+0)*H1 + j] = w0 * dd;
            bufA[DH0 + (t*2+1)*H1 + j] = w1 * dd;
        }
    }
    __syncthreads();

    // ---- tm1 L2 primal (100->100): h2 = tanh(h1@W2+b2)   bufA.h -> bufB.h
    if (j < H1) {
        float acc[16];
        #pragma unroll
        for (int tt = 0; tt < 16; ++tt) acc[tt] = 0.f;
        #pragma unroll 1
        for (int k = 0; k < H1; k += 4) {
            float w0 = tm1_w2[(k+0)*H1+j], w1 = tm1_w2[(k+1)*H1+j];
            float w2 = tm1_w2[(k+2)*H1+j], w3 = tm1_w2[(k+3)*H1+j];
            #pragma unroll
            for (int tt = 0; tt < 16; ++tt) {
                const float4 a = *(const float4*)&bufA[(th*16+tt)*H1 + k];
                acc[tt] += a.x*w0 + a.y*w1 + a.z*w2 + a.w*w3;
            }
        }
        float b = tm1_b2[j];
        #pragma unroll
        for (int tt = 0; tt < 16; ++tt) bufB[(th*16+tt)*H1 + j] = tanhf(acc[tt] + b);
    }
    __syncthreads();

    // ---- tm1 L2 tangent: dh2 = (dh1@W2)*(1-h2^2)   bufA.dh -> bufB.dh
    if (j < H1) {
        float acc[TPTS];
        #pragma unroll
        for (int t = 0; t < TPTS; ++t) acc[t] = 0.f;
        #pragma unroll 1
        for (int k = 0; k < H1; k += 4) {
            float w0 = tm1_w2[(k+0)*H1+j], w1 = tm1_w2[(k+1)*H1+j];
            float w2 = tm1_w2[(k+2)*H1+j], w3 = tm1_w2[(k+3)*H1+j];
            #pragma unroll
            for (int t = 0; t < TPTS; ++t) {
                const float4 a = *(const float4*)&bufA[DH0 + (t*2+dT)*H1 + k];
                acc[t] += a.x*w0 + a.y*w1 + a.z*w2 + a.w*w3;
            }
        }
        #pragma unroll
        for (int t = 0; t < TPTS; ++t) {
            float h = bufB[t*H1 + j];
            bufB[DH0 + (t*2+dT)*H1 + j] = acc[t] * (1.f - h*h);
        }
    }
    __syncthreads();

    // ---- tm1 L3 (100->2): y1 = h2@W3+b3+x ; dy1 = dh2@W3 + I
    if (tid < TPTS*2) {
        int t = tid >> 1, i = tid & 1;
        float a0 = 0.f, a1 = 0.f;
        #pragma unroll 1
        for (int k = 0; k < H1; k += 2) {
            a0 += bufB[t*H1 + k]     * tm1_w3[k*2 + i];
            a1 += bufB[t*H1 + k + 1] * tm1_w3[(k+1)*2 + i];
        }
        y1s[t*2 + i] = a0 + a1 + tm1_b3[i] + xs[t*2 + i];
    } else if (tid >= 128) {
        int r = tid - 128;
        int t = r >> 2, d = (r >> 1) & 1, i = r & 1;
        float a0 = 0.f, a1 = 0.f;
        #pragma unroll 1
        for (int k = 0; k < H1; k += 2) {
            a0 += bufB[DH0 + (t*2+d)*H1 + k]     * tm1_w3[k*2 + i];
            a1 += bufB[DH0 + (t*2+d)*H1 + k + 1] * tm1_w3[(k+1)*2 + i];
        }
        dy1s[t*4 + d*2 + i] = a0 + a1 + ((d == i) ? 1.f : 0.f);
    }
    __syncthreads();

    // ---- tm2 L1 (2->100): g1 = elu(y1@W4+b4); dg1 = (dy1@W4)*elu'
    if (j < H1) {
        float w0 = tm2_w1[j], w1 = tm2_w1[H1 + j], b = tm2_b1[j];
        #pragma unroll
        for (int tt = 0; tt < 16; ++tt) {
            int t = th*16 + tt;
            float pre = fmaf(y1s[t*2+1], w1, fmaf(y1s[t*2], w0, b));
            float g = eluf(pre);
            bufA[t*H1 + j] = g;
            float dd = (pre > 0.f) ? 1.f : (g + 1.f);
            bufA[DH0 + (t*2+0)*H1 + j] = (dy1s[t*4+0]*w0 + dy1s[t*4+1]*w1) * dd;
            bufA[DH0 + (t*2+1)*H1 + j] = (dy1s[t*4+2]*w0 + dy1s[t*4+3]*w1) * dd;
        }
    }
    __syncthreads();

    // ---- tm2 L2 primal: g2 = elu(g1@W5+b5)   bufA.h -> bufB.h
    if (j < H1) {
        float acc[16];
        #pragma unroll
        for (int tt = 0; tt < 16; ++tt) acc[tt] = 0.f;
        #pragma unroll 1
        for (int k = 0; k < H1; k += 4) {
            float w0 = tm2_w2[(k+0)*H1+j], w1 = tm2_w2[(k+1)*H1+j];
            float w2 = tm2_w2[(k+2)*H1+j], w3 = tm2_w2[(k+3)*H1+j];
            #pragma unroll
            for (int tt = 0; tt < 16; ++tt) {
                const float4 a = *(const float4*)&bufA[(th*16+tt)*H1 + k];
                acc[tt] += a.x*w0 + a.y*w1 + a.z*w2 + a.w*w3;
            }
        }
        float b = tm2_b2[j];
        #pragma unroll
        for (int tt = 0; tt < 16; ++tt) bufB[(th*16+tt)*H1 + j] = eluf(acc[tt] + b);
    }
    __syncthreads();

    // ---- tm2 L2 tangent: dg2 = (dg1@W5)*elu'(g2)   bufA.dh -> bufB.dh
    if (j < H1) {
        float acc[TPTS];
        #pragma unroll
        for (int t = 0; t < TPTS; ++t) acc[t] = 0.f;
        #pragma unroll 1
        for (int k = 0; k < H1; k += 4) {
            float w0 = tm2_w2[(k+0)*H1+j], w1 = tm2_w2[(k+1)*H1+j];
            float w2 = tm2_w2[(k+2)*H1+j], w3 = tm2_w2[(k+3)*H1+j];
            #pragma unroll
            for (int t = 0; t < TPTS; ++t) {
                const float4 a = *(const float4*)&bufA[DH0 + (t*2+dT)*H1 + k];
                acc[t] += a.x*w0 + a.y*w1 + a.z*w2 + a.w*w3;
            }
        }
        #pragma unroll
        for (int t = 0; t < TPTS; ++t) {
            float g = bufB[t*H1 + j];
            float dd = (g >= 0.f) ? 1.f : (g + 1.f);   // elu' recovered from elu output
            bufB[DH0 + (t*2+dT)*H1 + j] = acc[t] * dd;
        }
    }
    __syncthreads();

    // ---- tm2 L3 (100->2): spre -> s, sigma ; dspre
    if (tid < TPTS*2) {
        int t = tid >> 1, i = tid & 1;
        float a0 = 0.f, a1 = 0.f;
        #pragma unroll 1
        for (int k = 0; k < H1; k += 2) {
            a0 += bufB[t*H1 + k]     * tm2_w3[k*2 + i];
            a1 += bufB[t*H1 + k + 1] * tm2_w3[(k+1)*2 + i];
        }
        float spre = a0 + a1 + tm2_b3[i];
        ss[t*2 + i]   = softplusf(spre);
        sigs[t*2 + i] = 1.f / (1.f + expf(-spre));
    } else if (tid >= 128) {
        int r = tid - 128;
        int t = r >> 2, d = (r >> 1) & 1, i = r & 1;
        float a0 = 0.f, a1 = 0.f;
        #pragma unroll 1
        for (int k = 0; k < H1; k += 2) {
            a0 += bufB[DH0 + (t*2+d)*H1 + k]     * tm2_w3[k*2 + i];
            a1 += bufB[DH0 + (t*2+d)*H1 + k + 1] * tm2_w3[(k+1)*2 + i];
        }
        dss[t*4 + d*2 + i] = a0 + a1;
    }
    __syncthreads();

    // ---- J and y
    if (tid < TPTS*4) {
        int t = tid >> 2, d = (tid >> 1) & 1, i = tid & 1;
        float dsv = dss[t*4 + d*2 + i] * sigs[t*2 + i];
        Js[t*4 + i*2 + d] = dsv * y1s[t*2 + i] + (1.f + ss[t*2 + i]) * dy1s[t*4 + d*2 + i];
    } else if (tid >= 192) {
        int r = tid - 192, t = r >> 1, i = r & 1;
        ys[t*2 + i] = (1.f + ss[t*2 + i]) * y1s[t*2 + i] - origin[i];
    }
    __syncthreads();

    // ---- vs L1 (2->100): leaky(x@Wvs1+bvs1) -> bufA.h
    if (j < H1) {
        float w0 = vs_w1[j], w1 = vs_w1[H1 + j], b = vs_b1[j];
        #pragma unroll
        for (int tt = 0; tt < 16; ++tt) {
            int t = th*16 + tt;
            float pre = fmaf(xs[t*2+1], w1, fmaf(xs[t*2], w0, b));
            bufA[t*H1 + j] = leakyf(pre);
        }
    }
    __syncthreads();

    // ---- vs L2 (100->100) -> bufB.h
    if (j < H1) {
        float acc[16];
        #pragma unroll
        for (int tt = 0; tt < 16; ++tt) acc[tt] = 0.f;
        #pragma unroll 1
        for (int k = 0; k < H1; k += 4) {
            float w0 = vs_w2[(k+0)*H1+j], w1 = vs_w2[(k+1)*H1+j];
            float w2 = vs_w2[(k+2)*H1+j], w3 = vs_w2[(k+3)*H1+j];
            #pragma unroll
            for (int tt = 0; tt < 16; ++tt) {
                const float4 a = *(const float4*)&bufA[(th*16+tt)*H1 + k];
                acc[tt] += a.x*w0 + a.y*w1 + a.z*w2 + a.w*w3;
            }
        }
        float b = vs_b2[j];
        #pragma unroll
        for (int tt = 0; tt < 16; ++tt) bufB[(th*16+tt)*H1 + j] = leakyf(acc[tt] + b);
    }
    __syncthreads();

    // ---- vs L3 (100->1) -> lvs
    if (tid < TPTS) {
        float a0 = 0.f, a1 = 0.f;
        #pragma unroll 1
        for (int k = 0; k < H1; k += 2) {
            a0 += bufB[tid*H1 + k]     * vs_w3[k];
            a1 += bufB[tid*H1 + k + 1] * vs_w3[k + 1];
        }
        lvs[tid] = a0 + a1 + vs_b3[0];
    }
    __syncthreads();

    // ---- vv L1 (2->300): prelu(y@Wvv1+bvv1, a1) -> bufA (full 300/pt)
    for (int jj = j; jj < H3; jj += 128) {
        float w0 = vv_w1[jj], w1 = vv_w1[H3 + jj], b = vv_b1[jj];
        #pragma unroll
        for (int tt = 0; tt < 16; ++tt) {
            int t = th*16 + tt;
            float pre = fmaf(ys[t*2+1], w1, fmaf(ys[t*2], w0, b));
            bufA[t*H3 + jj] = preluf(pre, a1v);
        }
    }
    __syncthreads();

    // ---- vv L2 (300->300): the heavy layer. 3 columns/thread (clamped), 16 pts.
    {
        int ja = j, jb = j + 128;
        bool has_c = (j + 256 < H3);
        int jc = has_c ? (j + 256) : (H3 - 1);       // clamp -> redundant compute, store-guarded
        float accA[16], accB[16], accC[16];
        #pragma unroll
        for (int tt = 0; tt < 16; ++tt) { accA[tt] = 0.f; accB[tt] = 0.f; accC[tt] = 0.f; }
        #pragma unroll 1
        for (int k = 0; k < H3; k += 4) {
            float wa0 = vv_w2[(k+0)*H3+ja], wa1 = vv_w2[(k+1)*H3+ja], wa2 = vv_w2[(k+2)*H3+ja], wa3 = vv_w2[(k+3)*H3+ja];
            float wb0 = vv_w2[(k+0)*H3+jb], wb1 = vv_w2[(k+1)*H3+jb], wb2 = vv_w2[(k+2)*H3+jb], wb3 = vv_w2[(k+3)*H3+jb];
            float wc0 = vv_w2[(k+0)*H3+jc], wc1 = vv_w2[(k+1)*H3+jc], wc2 = vv_w2[(k+2)*H3+jc], wc3 = vv_w2[(k+3)*H3+jc];
            #pragma unroll
            for (int tt = 0; tt < 16; ++tt) {
                const float4 a = *(const float4*)&bufA[(th*16+tt)*H3 + k];
                accA[tt] += a.x*wa0 + a.y*wa1 + a.z*wa2 + a.w*wa3;
                accB[tt] += a.x*wb0 + a.y*wb1 + a.z*wb2 + a.w*wb3;
                accC[tt] += a.x*wc0 + a.y*wc1 + a.z*wc2 + a.w*wc3;
            }
        }
        #pragma unroll
        for (int tt = 0; tt < 16; ++tt) {
            int t = th*16 + tt;
            bufB[t*H3 + ja] = preluf(accA[tt] + vv_b2[ja], a2v);
            bufB[t*H3 + jb] = preluf(accB[tt] + vv_b2[jb], a2v);
            if (has_c) bufB[t*H3 + jc] = preluf(accC[tt] + vv_b2[jc], a2v);
        }
    }
    __syncthreads();

    // ---- vv L3 (300->2): doty
    if (tid < TPTS*2) {
        int t = tid >> 1, i = tid & 1;
        float a0 = 0.f, a1 = 0.f, a2 = 0.f, a3 = 0.f;
        #pragma unroll 1
        for (int k = 0; k < H3; k += 4) {
            a0 += bufB[t*H3 + k + 0] * vv_w3[(k+0)*2 + i];
            a1 += bufB[t*H3 + k + 1] * vv_w3[(k+1)*2 + i];
            a2 += bufB[t*H3 + k + 2] * vv_w3[(k+2)*2 + i];
            a3 += bufB[t*H3 + k + 3] * vv_w3[(k+3)*2 + i];
        }
        dotys[t*2 + i] = a0 + a1 + a2 + a3 + vv_b3[i];
    }
    __syncthreads();

    // ---- combine per point & store
    if (tid < TPTS) {
        int t = tid;
        int p = p0 + t;
        if (p < npts) {
            float y0 = ys[t*2], y1v = ys[t*2+1];
            float dt0 = dotys[t*2], dt1 = dotys[t*2+1];
            float ls = dt0*y0 + dt1*y1v;
            float V  = y0*y0 + y1v*y1v;
            float coef = fmaxf(ls + 1e-4f*V, 0.f) / (V + 1e-12f);
            float yd0 = dt0 - coef*y0, yd1 = dt1 - coef*y1v;
            float nrm = sqrtf(yd0*yd0 + yd1*yd1);
            float inv_n = 1.f / fmaxf(nrm, 1e-12f);
            float yn0 = yd0*inv_n, yn1 = yd1*inv_n;
            // J = [[Ja,Jb],[Jc,Jd]] (row i, col d); pinv == inv for well-conditioned 2x2
            float Ja = Js[t*4+0], Jb = Js[t*4+1], Jc = Js[t*4+2], Jd = Js[t*4+3];
            float invdet = 1.f / (Ja*Jd - Jb*Jc);
            float xh0 = ( Jd*yn0 - Jb*yn1) * invdet;
            float xh1 = (-Jc*yn0 + Ja*yn1) * invdet;
            float lv = lvs[t];
            float e0 = expf(lv + xs[t*2+0]) + 1e-12f;
            float e1 = expf(lv + xs[t*2+1]) + 1e-12f;
            out[p*2+0] = e0 * xh0;
            out[p*2+1] = e1 * xh1;
        }
    }
}

extern "C" void kernel_launch(void* const* d_in, const int* in_sizes, int n_in,
                              void* d_out, int out_size, void* d_ws, size_t ws_size,
                              hipStream_t stream) {
    const float* x      = (const float*)d_in[0];
    const float* tm1_w1 = (const float*)d_in[1];
    const float* tm1_b1 = (const float*)d_in[2];
    const float* tm1_w2 = (const float*)d_in[3];
    const float* tm1_b2 = (const float*)d_in[4];
    const float* tm1_w3 = (const float*)d_in[5];
    const float* tm1_b3 = (const float*)d_in[6];
    const float* tm2_w1 = (const float*)d_in[7];
    const float* tm2_b1 = (const float*)d_in[8];
    const float* tm2_w2 = (const float*)d_in[9];
    const float* tm2_b2 = (const float*)d_in[10];
    const float* tm2_w3 = (const float*)d_in[11];
    const float* tm2_b3 = (const float*)d_in[12];
    const float* vv_w1  = (const float*)d_in[13];
    const float* vv_b1  = (const float*)d_in[14];
    const float* vv_a1  = (const float*)d_in[15];
    const float* vv_w2  = (const float*)d_in[16];
    const float* vv_b2  = (const float*)d_in[17];
    const float* vv_a2  = (const float*)d_in[18];
    const float* vv_w3  = (const float*)d_in[19];
    const float* vv_b3  = (const float*)d_in[20];
    const float* vs_w1  = (const float*)d_in[21];
    const float* vs_b1  = (const float*)d_in[22];
    const float* vs_w2  = (const float*)d_in[23];
    const float* vs_b2  = (const float*)d_in[24];
    const float* vs_w3  = (const float*)d_in[25];
    const float* vs_b3  = (const float*)d_in[26];

    float* out = (float*)d_out;
    float* origin_ws = (float*)d_ws;
    const int npts = in_sizes[0] / 2;
    const int nblk = (npts + TPTS - 1) / TPTS;

    ngdv_origin<<<1, 128, 0, stream>>>(
        tm1_w1, tm1_b1, tm1_w2, tm1_b2, tm1_w3, tm1_b3,
        tm2_w1, tm2_b1, tm2_w2, tm2_b2, tm2_w3, tm2_b3,
        origin_ws);

    ngdv_main<<<nblk, 256, 0, stream>>>(
        x,
        tm1_w1, tm1_b1, tm1_w2, tm1_b2, tm1_w3, tm1_b3,
        tm2_w1, tm2_b1, tm2_w2, tm2_b2, tm2_w3, tm2_b3,
        vv_w1, vv_b1, vv_a1, vv_w2, vv_b2, vv_a2, vv_w3, vv_b3,
        vs_w1, vs_b1, vs_w2, vs_b2, vs_w3, vs_b3,
        origin_ws, out, npts);
}

// Round 2
// 474.001 us; speedup vs baseline: 2.6595x; 2.6595x over previous
//
#include <hip/hip_runtime.h>
#include <math.h>

#define TPTS 32            // points per block tile
#define H1   100           // taskmap / vs hidden
#define H3   300           // vv hidden
#define SA   136           // row stride (bf16) for taskmap-phase buffers (K=128 pad + 8 bank-skew)
#define SV   328           // row stride (bf16) for vv-phase buffers (K=320 pad + 8)
#define BIGN 13056         // max(96*SA, 32*SV) elements

// bf16 W^T regions inside d_ws (element offsets into short* at byte 64)
#define WT_TM1 0
#define WT_TM2 14336       // 112*128
#define WT_VS  28672
#define WT_VV  43008       // 304*320 follows
#define WT_TOTAL (43008 + 97280)

typedef __attribute__((ext_vector_type(8))) short s8v;   // 8 bf16 (4 VGPRs)
typedef __attribute__((ext_vector_type(4))) float f4v;   // MFMA accumulator

__device__ __forceinline__ float eluf(float v)      { return v > 0.f ? v : expm1f(v); }
__device__ __forceinline__ float softplusf(float v) { return v > 20.f ? v : log1pf(expf(v)); }
__device__ __forceinline__ float leakyf(float v)    { return v >= 0.f ? v : 0.01f * v; }
__device__ __forceinline__ float preluf(float v, float a) { return v >= 0.f ? v : a * v; }

__device__ __forceinline__ short f2bf(float f) {
    union { float f; unsigned u; } v; v.f = f;
    unsigned r = v.u + 0x7fffu + ((v.u >> 16) & 1u);   // RNE
    return (short)(r >> 16);
}
__device__ __forceinline__ float bf2f(short s) {
    union { unsigned u; float f; } v; v.u = ((unsigned)(unsigned short)s) << 16; return v.f;
}

// ---------------------------------------------------------------------------
// Weight prep: fp32 W[K][N] -> bf16 W^T[Npad][Kpad] zero-padded (runs every launch)
// ---------------------------------------------------------------------------
__global__ void ngdv_prep(const float* __restrict__ w_tm1, const float* __restrict__ w_tm2,
                          const float* __restrict__ w_vs,  const float* __restrict__ w_vv,
                          short* __restrict__ out)
{
    int idx = blockIdx.x * blockDim.x + threadIdx.x;
    if (idx < 3 * 14336) {
        int rgn = idx / 14336, r = idx % 14336;
        int n = r / 128, k = r % 128;
        const float* src = (rgn == 0) ? w_tm1 : (rgn == 1) ? w_tm2 : w_vs;
        float v = (n < H1 && k < H1) ? src[k * H1 + n] : 0.f;
        out[rgn * 14336 + n * 128 + k] = f2bf(v);
    } else if (idx < WT_TOTAL) {
        int r = idx - 3 * 14336;
        int n = r / 320, k = r % 320;
        float v = (n < H3 && k < H3) ? w_vv[k * H3 + n] : 0.f;
        out[WT_VV + n * 320 + k] = f2bf(v);
    }
}

// ---------------------------------------------------------------------------
// origin_y = taskmap(zeros(1,2)) — weights only, fp32
// ---------------------------------------------------------------------------
__global__ void ngdv_origin(
    const float* __restrict__ tm1_w1, const float* __restrict__ tm1_b1,
    const float* __restrict__ tm1_w2, const float* __restrict__ tm1_b2,
    const float* __restrict__ tm1_w3, const float* __restrict__ tm1_b3,
    const float* __restrict__ tm2_w1, const float* __restrict__ tm2_b1,
    const float* __restrict__ tm2_w2, const float* __restrict__ tm2_b2,
    const float* __restrict__ tm2_w3, const float* __restrict__ tm2_b3,
    float* __restrict__ origin_out)
{
    __shared__ float h1[H1], h2[H1], y1o[2], g1[H1], g2[H1];
    const int tid = threadIdx.x;   // 128 threads
    if (tid < H1) h1[tid] = tanhf(tm1_b1[tid]);
    __syncthreads();
    if (tid < H1) {
        float acc = tm1_b2[tid];
        for (int k = 0; k < H1; ++k) acc += h1[k] * tm1_w2[k*H1 + tid];
        h2[tid] = tanhf(acc);
    }
    __syncthreads();
    if (tid < 2) {
        float acc = tm1_b3[tid];
        for (int k = 0; k < H1; ++k) acc += h2[k] * tm1_w3[k*2 + tid];
        y1o[tid] = acc;
    }
    __syncthreads();
    if (tid < H1) g1[tid] = eluf(tm2_b1[tid] + y1o[0]*tm2_w1[tid] + y1o[1]*tm2_w1[H1 + tid]);
    __syncthreads();
    if (tid < H1) {
        float acc = tm2_b2[tid];
        for (int k = 0; k < H1; ++k) acc += g1[k] * tm2_w2[k*H1 + tid];
        g2[tid] = eluf(acc);
    }
    __syncthreads();
    if (tid < 2) {
        float acc = tm2_b3[tid];
        for (int k = 0; k < H1; ++k) acc += g2[k] * tm2_w3[k*2 + tid];
        origin_out[tid] = (1.f + softplusf(acc)) * y1o[tid];
    }
}

// ---------------------------------------------------------------------------
// Tiled MFMA GEMM: C[rows x N] = A[rows x K] @ W  with W^T[n][k] bf16 in global.
// B fragments register-cached per ntile; 16x16x32 bf16 MFMA.
// A layout: lane m=lane&15 reads k = quad*8 + j (16B contiguous)  [m120]
// B layout: lane n=lane&15 reads k = quad*8 + j from W^T          (mirror)
// C layout: col = lane&15, row = quad*4 + reg                      [m89]
// ---------------------------------------------------------------------------
template <int KSTEPS>
__device__ __forceinline__ void gemm_tiles(const short* Ain, short* Cout,
    const short* __restrict__ wT, int ntiles, int mtiles, int astride, int Kpad,
    int fm, int fq, int wv)
{
    for (int nt = wv; nt < ntiles; nt += 4) {
        s8v breg[KSTEPS];
        const short* bp = wT + (nt*16 + fm) * Kpad + fq*8;
        #pragma unroll
        for (int ks = 0; ks < KSTEPS; ++ks) breg[ks] = *(const s8v*)(bp + ks*32);
        for (int mt = 0; mt < mtiles; ++mt) {
            f4v acc = {0.f, 0.f, 0.f, 0.f};
            const short* ap = Ain + (mt*16 + fm) * astride + fq*8;
            #pragma unroll
            for (int ks = 0; ks < KSTEPS; ++ks)
                acc = __builtin_amdgcn_mfma_f32_16x16x32_bf16(*(const s8v*)(ap + ks*32), breg[ks], acc, 0, 0, 0);
            int col  = nt*16 + fm;
            int row0 = mt*16 + fq*4;
            Cout[(row0+0)*astride + col] = f2bf(acc[0]);
            Cout[(row0+1)*astride + col] = f2bf(acc[1]);
            Cout[(row0+2)*astride + col] = f2bf(acc[2]);
            Cout[(row0+3)*astride + col] = f2bf(acc[3]);
        }
    }
}

// ---------------------------------------------------------------------------
// Main fused kernel. 32 points/block; taskmap GEMMs run M=96 (primal + 2 tangent
// rows, row = 32 + d*32 + p). All activations bf16 in LDS; zero-padded K cols.
// ---------------------------------------------------------------------------
__global__ __launch_bounds__(256, 2) void ngdv_main(
    const float* __restrict__ x,
    const float* __restrict__ tm1_w1, const float* __restrict__ tm1_b1,
    const float* __restrict__ tm1_b2,
    const float* __restrict__ tm1_w3, const float* __restrict__ tm1_b3,
    const float* __restrict__ tm2_w1, const float* __restrict__ tm2_b1,
    const float* __restrict__ tm2_b2,
    const float* __restrict__ tm2_w3, const float* __restrict__ tm2_b3,
    const float* __restrict__ vv_w1, const float* __restrict__ vv_b1, const float* __restrict__ vv_a1,
    const float* __restrict__ vv_b2, const float* __restrict__ vv_a2,
    const float* __restrict__ vv_w3, const float* __restrict__ vv_b3,
    const float* __restrict__ vs_w1, const float* __restrict__ vs_b1,
    const float* __restrict__ vs_b2,
    const float* __restrict__ vs_w3, const float* __restrict__ vs_b3,
    const short* __restrict__ wsb,   const float* __restrict__ origin,
    float* __restrict__ out, int npts)
{
    __shared__ short U[BIGN];
    __shared__ short V[BIGN];
    __shared__ float xs[64], y1s[64], dy1s[128], dss[128], ss[64], sigs[64],
                     ys[64], Js[128], lvs[32], dotys[64], w3s[600];

    const int tid  = threadIdx.x;
    const int p0   = blockIdx.x * TPTS;
    const int wv   = tid >> 6;
    const int lane = tid & 63;
    const int fm   = lane & 15;
    const int fq   = lane >> 4;
    const int j    = tid & 127;
    const int th   = tid >> 7;
    const float a1v = vv_a1[0], a2v = vv_a2[0];

    if (tid < 64) { int g = p0*2 + tid; xs[tid] = (g < npts*2) ? x[g] : 0.f; }
    if (tid < 200) w3s[tid] = tm1_w3[tid];     // stage tm1_w3 for S2
    __syncthreads();

    // ---- S1: tm1 L1 (2->100) + tangent seeds -> U (96 rows)
    {
        bool valid = j < H1;
        float w0 = 0.f, w1 = 0.f, b = 0.f;
        if (valid) { w0 = tm1_w1[j]; w1 = tm1_w1[H1 + j]; b = tm1_b1[j]; }
        #pragma unroll
        for (int tt = 0; tt < 16; ++tt) {
            int p = th*16 + tt;
            if (valid) {
                float pre = fmaf(xs[p*2+1], w1, fmaf(xs[p*2], w0, b));
                float h = tanhf(pre), dd = 1.f - h*h;
                U[p*SA + j] = f2bf(h);
                U[(32+p)*SA + j] = f2bf(w0*dd);
                U[(64+p)*SA + j] = f2bf(w1*dd);
            } else {
                U[p*SA + j] = 0; U[(32+p)*SA + j] = 0; U[(64+p)*SA + j] = 0;
            }
        }
    }
    __syncthreads();

    // ---- G1: [96x128] @ tm1_w2 -> V raw
    gemm_tiles<4>(U, V, wsb + WT_TM1, 7, 6, SA, 128, fm, fq, wv);
    __syncthreads();

    // ---- E1: tanh epilogue (primal), then tangent * (1-h^2)
    {
        bool valid = j < H1;
        float b = valid ? tm1_b2[j] : 0.f;
        #pragma unroll
        for (int tt = 0; tt < 16; ++tt) {
            int p = th*16 + tt;
            U[p*SA + j] = valid ? f2bf(tanhf(bf2f(V[p*SA + j]) + b)) : 0;
        }
    }
    __syncthreads();
    {
        bool valid = j < H1;
        #pragma unroll
        for (int tt = 0; tt < 16; ++tt) {
            int p = th*16 + tt;
            if (valid) {
                float h = bf2f(U[p*SA + j]), dd = 1.f - h*h;
                U[(32+p)*SA + j] = f2bf(bf2f(V[(32+p)*SA + j]) * dd);
                U[(64+p)*SA + j] = f2bf(bf2f(V[(64+p)*SA + j]) * dd);
            } else { U[(32+p)*SA + j] = 0; U[(64+p)*SA + j] = 0; }
        }
    }
    __syncthreads();

    // ---- S2: tm1 L3 (100->2): y1, dy1 (+I)
    if (tid < 192) {
        int r = tid >> 1, i = tid & 1;
        float acc = 0.f;
        for (int k = 0; k < 96; k += 8) {
            s8v av = *(const s8v*)&U[r*SA + k];
            #pragma unroll
            for (int q8 = 0; q8 < 8; ++q8) acc = fmaf(bf2f(av[q8]), w3s[(k+q8)*2 + i], acc);
        }
        for (int k = 96; k < 100; ++k) acc = fmaf(bf2f(U[r*SA + k]), w3s[k*2 + i], acc);
        if (r < 32) y1s[r*2 + i] = acc + tm1_b3[i] + xs[r*2 + i];
        else { int d = (r-32) >> 5, p = (r-32) & 31; dy1s[p*4 + d*2 + i] = acc + ((d == i) ? 1.f : 0.f); }
    }
    __syncthreads();

    // ---- S3: tm2 L1 (2->100) + tangent -> U ; stage tm2_w3
    if (tid < 200) w3s[tid] = tm2_w3[tid];
    {
        bool valid = j < H1;
        float w0 = 0.f, w1 = 0.f, b = 0.f;
        if (valid) { w0 = tm2_w1[j]; w1 = tm2_w1[H1 + j]; b = tm2_b1[j]; }
        #pragma unroll
        for (int tt = 0; tt < 16; ++tt) {
            int p = th*16 + tt;
            if (valid) {
                float pre = fmaf(y1s[p*2+1], w1, fmaf(y1s[p*2], w0, b));
                float g = eluf(pre), dd = (pre > 0.f) ? 1.f : (g + 1.f);
                U[p*SA + j] = f2bf(g);
                U[(32+p)*SA + j] = f2bf((dy1s[p*4+0]*w0 + dy1s[p*4+1]*w1) * dd);
                U[(64+p)*SA + j] = f2bf((dy1s[p*4+2]*w0 + dy1s[p*4+3]*w1) * dd);
            } else {
                U[p*SA + j] = 0; U[(32+p)*SA + j] = 0; U[(64+p)*SA + j] = 0;
            }
        }
    }
    __syncthreads();

    // ---- G2: [96x128] @ tm2_w2 -> V raw
    gemm_tiles<4>(U, V, wsb + WT_TM2, 7, 6, SA, 128, fm, fq, wv);
    __syncthreads();

    // ---- E2: elu epilogue + tangent * elu'
    {
        bool valid = j < H1;
        float b = valid ? tm2_b2[j] : 0.f;
        #pragma unroll
        for (int tt = 0; tt < 16; ++tt) {
            int p = th*16 + tt;
            U[p*SA + j] = valid ? f2bf(eluf(bf2f(V[p*SA + j]) + b)) : 0;
        }
    }
    __syncthreads();
    {
        bool valid = j < H1;
        #pragma unroll
        for (int tt = 0; tt < 16; ++tt) {
            int p = th*16 + tt;
            if (valid) {
                float g = bf2f(U[p*SA + j]), dd = (g >= 0.f) ? 1.f : (g + 1.f);
                U[(32+p)*SA + j] = f2bf(bf2f(V[(32+p)*SA + j]) * dd);
                U[(64+p)*SA + j] = f2bf(bf2f(V[(64+p)*SA + j]) * dd);
            } else { U[(32+p)*SA + j] = 0; U[(64+p)*SA + j] = 0; }
        }
    }
    __syncthreads();

    // ---- S4: tm2 L3 (100->2): s, sigma, ds
    if (tid < 192) {
        int r = tid >> 1, i = tid & 1;
        float acc = 0.f;
        for (int k = 0; k < 96; k += 8) {
            s8v av = *(const s8v*)&U[r*SA + k];
            #pragma unroll
            for (int q8 = 0; q8 < 8; ++q8) acc = fmaf(bf2f(av[q8]), w3s[(k+q8)*2 + i], acc);
        }
        for (int k = 96; k < 100; ++k) acc = fmaf(bf2f(U[r*SA + k]), w3s[k*2 + i], acc);
        if (r < 32) {
            float spre = acc + tm2_b3[i];
            ss[r*2 + i] = softplusf(spre);
            sigs[r*2 + i] = 1.f / (1.f + expf(-spre));
        } else { int d = (r-32) >> 5, p = (r-32) & 31; dss[p*4 + d*2 + i] = acc; }
    }
    __syncthreads();

    // ---- S4b: J, y
    if (tid < 128) {
        int t = tid >> 2, d = (tid >> 1) & 1, i = tid & 1;
        float dsv = dss[t*4 + d*2 + i] * sigs[t*2 + i];
        Js[t*4 + i*2 + d] = dsv * y1s[t*2 + i] + (1.f + ss[t*2 + i]) * dy1s[t*4 + d*2 + i];
    } else if (tid >= 192) {
        int r = tid - 192, t = r >> 1, i = r & 1;
        ys[t*2 + i] = (1.f + ss[t*2 + i]) * y1s[t*2 + i] - origin[i];
    }
    __syncthreads();

    // ---- S5: vs L1 (2->100) -> U rows 0..31 ; stage vs_w3
    if (tid < 100) w3s[tid] = vs_w3[tid];
    {
        bool valid = j < H1;
        float w0 = 0.f, w1 = 0.f, b = 0.f;
        if (valid) { w0 = vs_w1[j]; w1 = vs_w1[H1 + j]; b = vs_b1[j]; }
        #pragma unroll
        for (int tt = 0; tt < 16; ++tt) {
            int p = th*16 + tt;
            float pre = fmaf(xs[p*2+1], w1, fmaf(xs[p*2], w0, b));
            U[p*SA + j] = valid ? f2bf(leakyf(pre)) : 0;
        }
    }
    __syncthreads();

    // ---- G3: [32x128] @ vs_w2 -> V raw
    gemm_tiles<4>(U, V, wsb + WT_VS, 7, 2, SA, 128, fm, fq, wv);
    __syncthreads();

    // ---- E3: leaky epilogue
    {
        bool valid = j < H1;
        float b = valid ? vs_b2[j] : 0.f;
        #pragma unroll
        for (int tt = 0; tt < 16; ++tt) {
            int p = th*16 + tt;
            if (valid) U[p*SA + j] = f2bf(leakyf(bf2f(V[p*SA + j]) + b));
        }
    }
    __syncthreads();

    // ---- S6: vs L3 (100->1) -> lvs
    if (tid < 32) {
        float acc = 0.f;
        for (int k = 0; k < 96; k += 8) {
            s8v av = *(const s8v*)&U[tid*SA + k];
            #pragma unroll
            for (int q8 = 0; q8 < 8; ++q8) acc = fmaf(bf2f(av[q8]), w3s[k+q8], acc);
        }
        for (int k = 96; k < 100; ++k) acc = fmaf(bf2f(U[tid*SA + k]), w3s[k], acc);
        lvs[tid] = acc + vs_b3[0];
    }
    __syncthreads();

    // ---- S7: vv L1 (2->300) -> U rows 0..31 stride SV ; stage vv_w3
    for (int q = tid; q < 600; q += 256) w3s[q] = vv_w3[q];
    {
        for (int jj = j; jj < 320; jj += 128) {
            bool valid = jj < H3;
            float w0 = 0.f, w1 = 0.f, b = 0.f;
            if (valid) { w0 = vv_w1[jj]; w1 = vv_w1[H3 + jj]; b = vv_b1[jj]; }
            #pragma unroll
            for (int tt = 0; tt < 16; ++tt) {
                int p = th*16 + tt;
                float pre = fmaf(ys[p*2+1], w1, fmaf(ys[p*2], w0, b));
                U[p*SV + jj] = valid ? f2bf(preluf(pre, a1v)) : 0;
            }
        }
    }
    __syncthreads();

    // ---- G4: [32x320] @ vv_w2 -> V raw (19 ntiles, 10 ksteps)
    gemm_tiles<10>(U, V, wsb + WT_VV, 19, 2, SV, 320, fm, fq, wv);
    __syncthreads();

    // ---- E4: prelu(.,a2) epilogue
    {
        for (int jj = j; jj < H3; jj += 128) {
            float b = vv_b2[jj];
            #pragma unroll
            for (int tt = 0; tt < 16; ++tt) {
                int p = th*16 + tt;
                U[p*SV + jj] = f2bf(preluf(bf2f(V[p*SV + jj]) + b, a2v));
            }
        }
    }
    __syncthreads();

    // ---- S8: vv L3 (300->2) -> dotys
    if (tid < 64) {
        int t = tid >> 1, i = tid & 1;
        float acc = 0.f;
        for (int k = 0; k < 296; k += 8) {
            s8v av = *(const s8v*)&U[t*SV + k];
            #pragma unroll
            for (int q8 = 0; q8 < 8; ++q8) acc = fmaf(bf2f(av[q8]), w3s[(k+q8)*2 + i], acc);
        }
        for (int k = 296; k < 300; ++k) acc = fmaf(bf2f(U[t*SV + k]), w3s[k*2 + i], acc);
        dotys[t*2 + i] = acc + vv_b3[i];
    }
    __syncthreads();

    // ---- S9: combine & store
    if (tid < TPTS) {
        int t = tid, p = p0 + t;
        if (p < npts) {
            float y0 = ys[t*2], y1v = ys[t*2+1];
            float dt0 = dotys[t*2], dt1 = dotys[t*2+1];
            float ls = dt0*y0 + dt1*y1v;
            float Vq = y0*y0 + y1v*y1v;
            float coef = fmaxf(ls + 1e-4f*Vq, 0.f) / (Vq + 1e-12f);
            float yd0 = dt0 - coef*y0, yd1 = dt1 - coef*y1v;
            float nrm = sqrtf(yd0*yd0 + yd1*yd1);
            float inv_n = 1.f / fmaxf(nrm, 1e-12f);
            float yn0 = yd0*inv_n, yn1 = yd1*inv_n;
            float Ja = Js[t*4+0], Jb = Js[t*4+1], Jc = Js[t*4+2], Jd = Js[t*4+3];
            float invdet = 1.f / (Ja*Jd - Jb*Jc);
            float xh0 = ( Jd*yn0 - Jb*yn1) * invdet;
            float xh1 = (-Jc*yn0 + Ja*yn1) * invdet;
            float lv = lvs[t];
            out[p*2+0] = (expf(lv + xs[t*2+0]) + 1e-12f) * xh0;
            out[p*2+1] = (expf(lv + xs[t*2+1]) + 1e-12f) * xh1;
        }
    }
}

extern "C" void kernel_launch(void* const* d_in, const int* in_sizes, int n_in,
                              void* d_out, int out_size, void* d_ws, size_t ws_size,
                              hipStream_t stream) {
    const float* x      = (const float*)d_in[0];
    const float* tm1_w1 = (const float*)d_in[1];
    const float* tm1_b1 = (const float*)d_in[2];
    const float* tm1_w2 = (const float*)d_in[3];
    const float* tm1_b2 = (const float*)d_in[4];
    const float* tm1_w3 = (const float*)d_in[5];
    const float* tm1_b3 = (const float*)d_in[6];
    const float* tm2_w1 = (const float*)d_in[7];
    const float* tm2_b1 = (const float*)d_in[8];
    const float* tm2_w2 = (const float*)d_in[9];
    const float* tm2_b2 = (const float*)d_in[10];
    const float* tm2_w3 = (const float*)d_in[11];
    const float* tm2_b3 = (const float*)d_in[12];
    const float* vv_w1  = (const float*)d_in[13];
    const float* vv_b1  = (const float*)d_in[14];
    const float* vv_a1  = (const float*)d_in[15];
    const float* vv_w2  = (const float*)d_in[16];
    const float* vv_b2  = (const float*)d_in[17];
    const float* vv_a2  = (const float*)d_in[18];
    const float* vv_w3  = (const float*)d_in[19];
    const float* vv_b3  = (const float*)d_in[20];
    const float* vs_w1  = (const float*)d_in[21];
    const float* vs_b1  = (const float*)d_in[22];
    const float* vs_w2  = (const float*)d_in[23];
    const float* vs_b2  = (const float*)d_in[24];
    const float* vs_w3  = (const float*)d_in[25];
    const float* vs_b3  = (const float*)d_in[26];

    float* out       = (float*)d_out;
    float* origin_ws = (float*)d_ws;                       // 2 floats
    short* wsb       = (short*)((char*)d_ws + 64);         // bf16 W^T regions
    const int npts = in_sizes[0] / 2;
    const int nblk = (npts + TPTS - 1) / TPTS;

    ngdv_prep<<<(WT_TOTAL + 255) / 256, 256, 0, stream>>>(tm1_w2, tm2_w2, vs_w2, vv_w2, wsb);

    ngdv_origin<<<1, 128, 0, stream>>>(
        tm1_w1, tm1_b1, tm1_w2, tm1_b2, tm1_w3, tm1_b3,
        tm2_w1, tm2_b1, tm2_w2, tm2_b2, tm2_w3, tm2_b3,
        origin_ws);

    ngdv_main<<<nblk, 256, 0, stream>>>(
        x,
        tm1_w1, tm1_b1, tm1_b2, tm1_w3, tm1_b3,
        tm2_w1, tm2_b1, tm2_b2, tm2_w3, tm2_b3,
        vv_w1, vv_b1, vv_a1, vv_b2, vv_a2, vv_w3, vv_b3,
        vs_w1, vs_b1, vs_b2, vs_w3, vs_b3,
        wsb, origin_ws, out, npts);
}